// Round 1
// baseline (289.183 us; speedup 1.0000x reference)
//
#include <hip/hip_runtime.h>

#define NBINS 10
#define PART_STRIDE 32   // per-block partial row stride (padded from 30)

// Round 4: register histogram. 10 bins fit in 20 VGPRs/thread:
// pacc[10] f32 prob sums + cacc[10] packed (tp<<16 | count) u32.
// Per element: same exact bin computation as before, then a fully
// unrolled 10-way compare/select/add (~5 VALU/bin, one v_cmp reused for
// both cndmasks). No LDS in the hot loop -> no ds RMW latency chain,
// no lgkmcnt stalls, 8 blocks/CU. Manual next-iter prefetch keeps the
// 2 dwordx4 loads in flight under the VALU phase.
__global__ __launch_bounds__(256) void calib_hist(
    const float* __restrict__ outputs,
    const float* __restrict__ labels,
    float* __restrict__ partials,
    long n)
{
    const int tid = threadIdx.x;
    const float low0 = -1e-6f;
    const float step = (1.0f - low0) / 10.0f;   // fp32 linspace delta (const-folded)

    float        pacc[NBINS];
    unsigned int cacc[NBINS];
#pragma unroll
    for (int j = 0; j < NBINS; ++j) { pacc[j] = 0.0f; cacc[j] = 0u; }

    const long total4 = n >> 2;
    const float4* o4 = (const float4*)outputs;
    const float4* l4 = (const float4*)labels;
    const long gid = (long)blockIdx.x * blockDim.x + tid;
    const long gsz = (long)gridDim.x * blockDim.x;

    long i = gid;
    if (i < total4) {
        float4 o = o4[i];
        float4 l = l4[i];
        for (;;) {
            const long nexti = i + gsz;
            const bool have_next = (nexti < total4);
            float4 no, nl;
            if (have_next) { no = o4[nexti]; nl = l4[nexti]; }

            float xs[4] = {o.x, o.y, o.z, o.w};
            float ys[4] = {l.x, l.y, l.z, l.w};
#pragma unroll
            for (int k = 0; k < 4; ++k) {
                float x = xs[k];
                bool valid = (x > low0) & (x <= 1.0f);
                int e = (int)(x * 10.0f);
                e = e < 0 ? 0 : (e > 9 ? 9 : e);
                float fe  = (float)e;
                float hb0 = fmaf(fe,        step, low0);   // high[e-1]
                float hb1 = fmaf(fe + 1.0f, step, low0);   // high[e]
                int b = e + ((x > hb1) ? 1 : 0) - (((e > 0) & (x <= hb0)) ? 1 : 0);
                b = b < 0 ? 0 : (b > 9 ? 9 : b);
                b = valid ? b : NBINS;                      // invalid: matches no bin
                unsigned int pc = (ys[k] > 0.5f) ? 0x10001u : 1u;
#pragma unroll
                for (int j = 0; j < NBINS; ++j) {
                    bool hit = (b == j);                    // one v_cmp, vcc reused
                    pacc[j] += hit ? x : 0.0f;
                    cacc[j] += hit ? pc : 0u;
                }
            }

            if (!have_next) break;
            o = no; l = nl; i = nexti;
        }
    }

    // scalar tail for n % 4 != 0 (not hit for this shape)
    const long tail0 = total4 << 2;
    for (long t = tail0 + gid; t < n; t += gsz) {
        float x = outputs[t];
        float y = labels [t];
        bool valid = (x > low0) & (x <= 1.0f);
        int e = (int)(x * 10.0f);
        e = e < 0 ? 0 : (e > 9 ? 9 : e);
        float fe  = (float)e;
        float hb0 = fmaf(fe,        step, low0);
        float hb1 = fmaf(fe + 1.0f, step, low0);
        int b = e + ((x > hb1) ? 1 : 0) - (((e > 0) & (x <= hb0)) ? 1 : 0);
        b = b < 0 ? 0 : (b > 9 ? 9 : b);
        b = valid ? b : NBINS;
        unsigned int pc = (y > 0.5f) ? 0x10001u : 1u;
#pragma unroll
        for (int j = 0; j < NBINS; ++j) {
            bool hit = (b == j);
            pacc[j] += hit ? x : 0.0f;
            cacc[j] += hit ? pc : 0u;
        }
    }

    // Wave butterfly reduce (64 lanes). Unpack counts first so the 16-bit
    // fields can never overflow during the cross-lane sum.
    __shared__ float s_red[4][32];   // [wave][slot], 30 slots used (512 B)
    const int lane = tid & 63;
    const int wave = tid >> 6;
#pragma unroll
    for (int j = 0; j < NBINS; ++j) {
        float p  = pacc[j];
        float tp = (float)(cacc[j] >> 16);
        float ct = (float)(cacc[j] & 0xFFFFu);
#pragma unroll
        for (int off = 32; off > 0; off >>= 1) {
            p  += __shfl_xor(p,  off, 64);
            tp += __shfl_xor(tp, off, 64);
            ct += __shfl_xor(ct, off, 64);
        }
        if (lane == 0) {
            s_red[wave][j]             = p;
            s_red[wave][NBINS + j]     = tp;
            s_red[wave][2 * NBINS + j] = ct;
        }
    }
    __syncthreads();
    if (tid < 3 * NBINS) {
        float s = s_red[0][tid] + s_red[1][tid] + s_red[2][tid] + s_red[3][tid];
        partials[(long)blockIdx.x * PART_STRIDE + tid] = s;
    }
}

// Kernel 2: one block per output slot; double-precision accumulate of partials.
__global__ __launch_bounds__(256) void calib_reduce(
    const float* __restrict__ partials, float* __restrict__ out, int nrows)
{
    const int s   = blockIdx.x;    // 0..29
    const int tid = threadIdx.x;
    double acc = 0.0;
    for (int r = tid; r < nrows; r += 256)
        acc += (double)partials[(long)r * PART_STRIDE + s];
#pragma unroll
    for (int off = 32; off > 0; off >>= 1)
        acc += __shfl_down(acc, off, 64);
    __shared__ double wsum[4];
    if ((tid & 63) == 0) wsum[tid >> 6] = acc;
    __syncthreads();
    if (tid == 0) out[s] = (float)(wsum[0] + wsum[1] + wsum[2] + wsum[3]);
}

extern "C" void kernel_launch(void* const* d_in, const int* in_sizes, int n_in,
                              void* d_out, int out_size, void* d_ws, size_t ws_size,
                              hipStream_t stream) {
    const float* outputs = (const float*)d_in[0];
    const float* labels  = (const float*)d_in[1];
    float* out = (float*)d_out;
    long n = (long)in_sizes[0];

    // No big LDS tile anymore: reg-bound occupancy ~8 blocks/CU.
    // grid = 2048 -> exactly 16 float4 per thread at this shape;
    // per-lane count <= 68 so the packed 16-bit fields stay exact.
    int nblocks = 2048;
    size_t need = (size_t)nblocks * PART_STRIDE * sizeof(float);
    if (ws_size < need) {
        nblocks = (int)(ws_size / (PART_STRIDE * sizeof(float)));
        if (nblocks < 1) nblocks = 1;
    }
    float* partials = (float*)d_ws;

    calib_hist  <<<nblocks, 256, 0, stream>>>(outputs, labels, partials, n);
    calib_reduce<<<3 * NBINS, 256, 0, stream>>>(partials, out, nblocks);
}